// Round 1
// baseline (17321.471 us; speedup 1.0000x reference)
//
#include <hip/hip_runtime.h>

// LSTM: S=512, B=128, I=1024, H=1024. Fused formulation:
//   gates[t] = [h_t | x_t] @ [w_hh | w_ih]^T + (b_ih + b_hh)   (K = 2048, bf16 MFMA, fp32 acc)
//   i,f,g,o = split(gates); c = f*c + i*g; h = o*tanh(c)
// One kernel launch per step (512 graph nodes); h double-buffered in ws.

#define S_LEN 512
#define BATCH 128
#define IDIM  1024
#define HDIM  1024

using short8 = __attribute__((ext_vector_type(8))) short;  // 8 x bf16 (4 VGPRs)
using f32x4  = __attribute__((ext_vector_type(4))) float;  // MFMA accumulator

__device__ __forceinline__ unsigned short f2bf(float f) {
  unsigned int u = __float_as_uint(f);
  u += 0x7fffu + ((u >> 16) & 1u);   // round-to-nearest-even
  return (unsigned short)(u >> 16);
}

__device__ __forceinline__ float sigf(float x) { return 1.f / (1.f + __expf(-x)); }
__device__ __forceinline__ float tanh_fast(float x) { return 2.f / (1.f + __expf(-2.f * x)) - 1.f; }

__global__ void cvt_bf16_kernel(const float* __restrict__ in, unsigned short* __restrict__ out, int n4) {
  int i = blockIdx.x * blockDim.x + threadIdx.x;
  if (i >= n4) return;
  const float4 v = ((const float4*)in)[i];
  ushort4 o;
  o.x = f2bf(v.x); o.y = f2bf(v.y); o.z = f2bf(v.z); o.w = f2bf(v.w);
  ((ushort4*)out)[i] = o;
}

__global__ void bias_sum_kernel(const float* __restrict__ a, const float* __restrict__ b,
                                float* __restrict__ o, int n) {
  int i = blockIdx.x * blockDim.x + threadIdx.x;
  if (i < n) o[i] = a[i] + b[i];
}

// One LSTM timestep. Grid: 64 blocks (block n -> h cols [16n,16n+16)); 512 threads = 8 waves.
// Wave w -> batch rows [16w,16w+16). Gate tile per block: [128 rows x 4 groups x 16 cols].
// K-loop: kt in [0,32), BK=64; kt<16 reads (h_in, w_hh), kt>=16 reads (x_t, w_ih).
__global__ __launch_bounds__(512) void lstm_step_kernel(
    const unsigned short* __restrict__ h_in,   // [128][1024] bf16
    const unsigned short* __restrict__ x_t,    // [128][1024] bf16 (timestep slice)
    const unsigned short* __restrict__ w_hh,   // [4096][1024] bf16
    const unsigned short* __restrict__ w_ih,   // [4096][1024] bf16
    const float* __restrict__ bias,            // [4096] = b_ih + b_hh
    float* __restrict__ cbuf,                  // [128][1024] fp32 cell state (in/out)
    float* __restrict__ out_t,                 // [128][1024] fp32 output slice
    unsigned short* __restrict__ h_out)        // [128][1024] bf16 next h
{
  constexpr int LDT = 72;  // padded LDS row (ushorts): 144 B = 16B-aligned, 2-way bank alias (free)
  __shared__ unsigned short ldsA[128 * LDT];   // A tile [128 rows][64 k]
  __shared__ unsigned short ldsB[64 * LDT];    // B tile [64 gate-rows][64 k]

  const int t    = threadIdx.x;
  const int lane = t & 63;
  const int wv   = t >> 6;       // wave 0..7
  const int blk  = blockIdx.x;   // 0..63

  f32x4 acc0 = {0.f, 0.f, 0.f, 0.f};  // i
  f32x4 acc1 = {0.f, 0.f, 0.f, 0.f};  // f
  f32x4 acc2 = {0.f, 0.f, 0.f, 0.f};  // g
  f32x4 acc3 = {0.f, 0.f, 0.f, 0.f};  // o

  // staging map: thread t -> A rows {t>>3, 64+(t>>3)}, B lds-row t>>3, 16B chunk (t&7)
  const int arow = t >> 3;       // 0..63
  const int kc   = t & 7;
  const int bgrp = arow >> 4;    // gate group 0..3
  const int brr  = arow & 15;
  const int wrow = (bgrp * 1024 + blk * 16 + brr) * 1024;  // weight row base (elements)

  const int mrow = lane & 15;    // MFMA frag row / C col
  const int q    = lane >> 4;

  for (int kt = 0; kt < 32; ++kt) {
    const unsigned short* Ab = (kt < 16) ? h_in : x_t;
    const unsigned short* Bb = (kt < 16) ? w_hh : w_ih;
    const int k0 = (kt & 15) * 64;
    __syncthreads();
    const uint4 va0 = *(const uint4*)(Ab + arow * 1024 + k0 + kc * 8);
    const uint4 va1 = *(const uint4*)(Ab + (64 + arow) * 1024 + k0 + kc * 8);
    const uint4 vb  = *(const uint4*)(Bb + wrow + k0 + kc * 8);
    *(uint4*)(ldsA + arow * LDT + kc * 8)        = va0;
    *(uint4*)(ldsA + (64 + arow) * LDT + kc * 8) = va1;
    *(uint4*)(ldsB + arow * LDT + kc * 8)        = vb;
    __syncthreads();
#pragma unroll
    for (int s = 0; s < 2; ++s) {
      const short8 a  = *(const short8*)(ldsA + (wv * 16 + mrow) * LDT + s * 32 + q * 8);
      const short8 b0 = *(const short8*)(ldsB + ( 0 + mrow) * LDT + s * 32 + q * 8);
      const short8 b1 = *(const short8*)(ldsB + (16 + mrow) * LDT + s * 32 + q * 8);
      const short8 b2 = *(const short8*)(ldsB + (32 + mrow) * LDT + s * 32 + q * 8);
      const short8 b3 = *(const short8*)(ldsB + (48 + mrow) * LDT + s * 32 + q * 8);
      acc0 = __builtin_amdgcn_mfma_f32_16x16x32_bf16(a, b0, acc0, 0, 0, 0);
      acc1 = __builtin_amdgcn_mfma_f32_16x16x32_bf16(a, b1, acc1, 0, 0, 0);
      acc2 = __builtin_amdgcn_mfma_f32_16x16x32_bf16(a, b2, acc2, 0, 0, 0);
      acc3 = __builtin_amdgcn_mfma_f32_16x16x32_bf16(a, b3, acc3, 0, 0, 0);
    }
  }

  // Epilogue: C/D layout col=lane&15 (gate col), row=q*4+r (batch row within wave tile)
  const int j = blk * 16 + mrow;  // h column
  const float b_i = bias[j];
  const float b_f = bias[1024 + j];
  const float b_g = bias[2048 + j];
  const float b_o = bias[3072 + j];
#pragma unroll
  for (int r = 0; r < 4; ++r) {
    const int m   = wv * 16 + q * 4 + r;   // batch row
    const int idx = m * 1024 + j;
    const float iv = sigf(acc0[r] + b_i);
    const float fv = sigf(acc1[r] + b_f);
    const float gv = tanh_fast(acc2[r] + b_g);
    const float ov = sigf(acc3[r] + b_o);
    const float cc = fv * cbuf[idx] + iv * gv;
    cbuf[idx] = cc;
    const float hh = ov * tanh_fast(cc);
    out_t[idx] = hh;
    h_out[idx] = f2bf(hh);
  }
}

extern "C" void kernel_launch(void* const* d_in, const int* in_sizes, int n_in,
                              void* d_out, int out_size, void* d_ws, size_t ws_size,
                              hipStream_t stream) {
  const float* x    = (const float*)d_in[0];
  const float* w_ih = (const float*)d_in[1];
  const float* w_hh = (const float*)d_in[2];
  const float* b_ih = (const float*)d_in[3];
  const float* b_hh = (const float*)d_in[4];
  float* out = (float*)d_out;

  char* ws = (char*)d_ws;
  const size_t XBF_OFF  = 0;                        // 512*128*1024*2 = 134217728
  const size_t WHH_OFF  = XBF_OFF + 134217728;      // 4096*1024*2    =   8388608
  const size_t WIH_OFF  = WHH_OFF + 8388608;
  const size_t BIAS_OFF = WIH_OFF + 8388608;        // 4096*4
  const size_t C_OFF    = BIAS_OFF + 16384;         // 128*1024*4
  const size_t H0_OFF   = C_OFF + 524288;           // 128*1024*2
  const size_t H1_OFF   = H0_OFF + 262144;          // 128*1024*2  (total ~145 MB)

  unsigned short* x_bf   = (unsigned short*)(ws + XBF_OFF);
  unsigned short* whh_bf = (unsigned short*)(ws + WHH_OFF);
  unsigned short* wih_bf = (unsigned short*)(ws + WIH_OFF);
  float*          bias   = (float*)(ws + BIAS_OFF);
  float*          cbuf   = (float*)(ws + C_OFF);
  unsigned short* h0     = (unsigned short*)(ws + H0_OFF);
  unsigned short* h1     = (unsigned short*)(ws + H1_OFF);

  // dtype conversions (ws is re-poisoned before every call, so redo every call)
  cvt_bf16_kernel<<<65536, 256, 0, stream>>>(x, x_bf, 16777216);       // 512*128*1024/4
  cvt_bf16_kernel<<<4096, 256, 0, stream>>>(w_ih, wih_bf, 1048576);    // 4096*1024/4
  cvt_bf16_kernel<<<4096, 256, 0, stream>>>(w_hh, whh_bf, 1048576);
  bias_sum_kernel<<<16, 256, 0, stream>>>(b_ih, b_hh, bias, 4096);
  hipMemsetAsync(cbuf, 0, 524288, stream);   // c0 = 0
  hipMemsetAsync(h0, 0, 262144, stream);     // h0 = 0

  unsigned short* hin  = h0;
  unsigned short* hout = h1;
  for (int t = 0; t < S_LEN; ++t) {
    lstm_step_kernel<<<64, 512, 0, stream>>>(
        hin, x_bf + (size_t)t * (BATCH * IDIM), whh_bf, wih_bf, bias, cbuf,
        out + (size_t)t * (BATCH * HDIM), hout);
    unsigned short* tmp = hin; hin = hout; hout = tmp;
  }

  // outputs: [S,B,H] (written per step) | hN [B,H] | cN [B,H]
  hipMemcpyAsync(out + (size_t)S_LEN * BATCH * HDIM,
                 out + (size_t)(S_LEN - 1) * BATCH * HDIM,
                 (size_t)BATCH * HDIM * sizeof(float), hipMemcpyDeviceToDevice, stream);
  hipMemcpyAsync(out + (size_t)S_LEN * BATCH * HDIM + BATCH * HDIM, cbuf,
                 (size_t)BATCH * HDIM * sizeof(float), hipMemcpyDeviceToDevice, stream);
}

// Round 2
// 7656.502 us; speedup vs baseline: 2.2623x; 2.2623x over previous
//
#include <hip/hip_runtime.h>

// LSTM S=512,B=128,I=H=1024. Round 2: staging-free step kernel.
// gates_t = [h_t | x_t] @ [w_hh | w_ih]^T + bias  (K=2048, bf16 MFMA, fp32 acc)
// Both operands pre-packed into MFMA a/b-frag order so the K-loop is pure
// coalesced global_load_dwordx4 (L2-hot) + MFMA. 8-way K-split across waves,
// LDS only for the final partial-reduction + fused activation epilogue.

#define S_LEN 512

using short8 = __attribute__((ext_vector_type(8))) short;  // 8 bf16 = one frag
using f32x4  = __attribute__((ext_vector_type(4))) float;

__device__ __forceinline__ unsigned short f2bf(float f) {
  unsigned int u = __float_as_uint(f);
  u += 0x7fffu + ((u >> 16) & 1u);   // RNE
  return (unsigned short)(u >> 16);
}
__device__ __forceinline__ unsigned int pk2(float a, float b) {
  return (unsigned int)f2bf(a) | ((unsigned int)f2bf(b) << 16);
}
__device__ __forceinline__ float sigf(float x)  { return 1.f / (1.f + __expf(-x)); }
__device__ __forceinline__ float tanhf_(float x){ return 2.f / (1.f + __expf(-2.f * x)) - 1.f; }

// ---- pack x: xp[t][rh2][kq4][ks8][rf4][ln64][8]  (a-frag order, bf16) ----
// a-frag mapping (16x16x32, m89-verified in round 1): row=lane&15, k=(lane>>4)*8+e
__global__ void xpack_kernel(const float* __restrict__ x, unsigned short* __restrict__ xp) {
  const int gid = blockIdx.x * 256 + threadIdx.x;     // 8,388,608 total
  const int t  = gid >> 14;
  const int u  = gid & 16383;
  const int ln = u & 63;
  const int u6 = u >> 6;            // (((rh*4+kq)*8+ks)*4+rf)
  const int rf = u6 & 3;
  const int ks = (u6 >> 2) & 7;
  const int kq = (u6 >> 5) & 3;
  const int rh = u6 >> 7;
  const int row = rh * 64 + rf * 16 + (ln & 15);
  const int i   = kq * 256 + ks * 32 + (ln >> 4) * 8;
  const float* src = x + ((size_t)t * 131072 + (size_t)row * 1024 + i);
  const float4 v0 = *(const float4*)src;
  const float4 v1 = *(const float4*)(src + 4);
  uint4 o;
  o.x = pk2(v0.x, v0.y); o.y = pk2(v0.z, v0.w);
  o.z = pk2(v1.x, v1.y); o.w = pk2(v1.z, v1.w);
  *(uint4*)(xp + (size_t)gid * 8) = o;
}

// ---- pack weights: wp[b64][kq8][ks8][cg4][ln64][8]  (b-frag order) ----
// fused K: kq<4 -> w_hh[k = kq*256+...], kq>=4 -> w_ih[k-1024]
__global__ void wpack_kernel(const float* __restrict__ w_hh, const float* __restrict__ w_ih,
                             unsigned short* __restrict__ wp) {
  const int gid = blockIdx.x * 256 + threadIdx.x;     // 1,048,576 total
  const int ln = gid & 63;
  const int u6 = gid >> 6;          // (((b*8+kq)*8+ks)*4+cg)
  const int cg = u6 & 3;
  const int ks = (u6 >> 2) & 7;
  const int kq = (u6 >> 5) & 7;
  const int b  = u6 >> 8;
  const int grow = cg * 1024 + b * 16 + (ln & 15);    // gate row
  const int k    = kq * 256 + ks * 32 + (ln >> 4) * 8;
  const float* src = (k < 1024) ? (w_hh + (size_t)grow * 1024 + k)
                                : (w_ih + (size_t)grow * 1024 + (k - 1024));
  const float4 v0 = *(const float4*)src;
  const float4 v1 = *(const float4*)(src + 4);
  uint4 o;
  o.x = pk2(v0.x, v0.y); o.y = pk2(v0.z, v0.w);
  o.z = pk2(v1.x, v1.y); o.w = pk2(v1.z, v1.w);
  *(uint4*)(wp + (size_t)gid * 8) = o;
}

__global__ void bias_sum_kernel(const float* __restrict__ a, const float* __restrict__ b,
                                float* __restrict__ o, int n) {
  int i = blockIdx.x * blockDim.x + threadIdx.x;
  if (i < n) o[i] = a[i] + b[i];
}

// ---- one LSTM step ----
// grid 128: block = (b = bid>>1 -> h-cols [16b,16b+16) x 4 gates, rh = bid&1 -> rows [64rh,64rh+64))
// 8 waves = 8-way K-split (256 K each); wave tile [64 rows x 64 gate-cols], acc 16 f32x4.
__global__ __launch_bounds__(512) void lstm_step(
    const unsigned short* __restrict__ hp_in,   // packed h  [rh2][kq4][ks8][rf4][ln64][8]
    const unsigned short* __restrict__ xp_t,    // packed x_t, same shape
    const unsigned short* __restrict__ wp,      // packed weights
    const float* __restrict__ bias,             // [4096]
    float* __restrict__ cbuf,                   // [128][1024] fp32
    float* __restrict__ out_t,                  // [128][1024] fp32
    unsigned short* __restrict__ hp_out)        // packed next h
{
  __shared__ float P[8][64][32];   // 64 KB: per-col-half partials
  const int tid  = threadIdx.x;
  const int lane = tid & 63;
  const int w    = tid >> 6;       // wave = kq 0..7
  const int b    = blockIdx.x >> 1;
  const int rh   = blockIdx.x & 1;

  const unsigned short* ab = (w < 4) ? (hp_in + (size_t)(rh * 4 + w) * 16384)
                                     : (xp_t  + (size_t)(rh * 4 + (w - 4)) * 16384);
  const unsigned short* bb = wp + (size_t)(b * 8 + w) * 16384;

  short8 afr[2][4], bfr[2][4];
#pragma unroll
  for (int rf = 0; rf < 4; ++rf) afr[0][rf] = *(const short8*)(ab + rf * 512 + lane * 8);
#pragma unroll
  for (int cg = 0; cg < 4; ++cg) bfr[0][cg] = *(const short8*)(bb + cg * 512 + lane * 8);

  f32x4 acc[4][4] = {};
#pragma unroll
  for (int ks = 0; ks < 8; ++ks) {
    const int cur = ks & 1, nxt = cur ^ 1;
    if (ks < 7) {
#pragma unroll
      for (int rf = 0; rf < 4; ++rf)
        afr[nxt][rf] = *(const short8*)(ab + ((ks + 1) * 4 + rf) * 512 + lane * 8);
#pragma unroll
      for (int cg = 0; cg < 4; ++cg)
        bfr[nxt][cg] = *(const short8*)(bb + ((ks + 1) * 4 + cg) * 512 + lane * 8);
    }
#pragma unroll
    for (int rf = 0; rf < 4; ++rf)
#pragma unroll
      for (int cg = 0; cg < 4; ++cg)
        acc[rf][cg] = __builtin_amdgcn_mfma_f32_16x16x32_bf16(afr[cur][rf], bfr[cur][cg], acc[rf][cg], 0, 0, 0);
  }

  // C/D layout (m89): col = lane&15 (gate col), row = (lane>>4)*4 + reg
  const int q     = lane >> 4;
  const int c15   = lane & 15;
  const int chalf = c15 >> 3;
  const int c8    = c15 & 7;

  for (int h = 0; h < 2; ++h) {
    __syncthreads();
    if (chalf == h) {
#pragma unroll
      for (int rf = 0; rf < 4; ++rf)
#pragma unroll
        for (int cg = 0; cg < 4; ++cg)
#pragma unroll
          for (int r = 0; r < 4; ++r)
            // q-skewed column to keep ds_writes conflict-free
            P[w][rf * 16 + q * 4 + r][(cg * 8 + c8 + (q << 3)) & 31] = acc[rf][cg][r];
    }
    __syncthreads();
    // epilogue: 512 cells = 64 rows x 8 h-cols; one cell per thread
    const int r64 = tid >> 3;
    const int ccc = tid & 7;
    const int j   = b * 16 + h * 8 + ccc;       // h column
    const int row = rh * 64 + r64;              // batch row
    const int sh  = ((r64 >> 2) & 3) << 3;      // matching de-skew
    float g4[4];
#pragma unroll
    for (int cg = 0; cg < 4; ++cg) {
      float s = 0.f;
#pragma unroll
      for (int kq = 0; kq < 8; ++kq) s += P[kq][r64][(cg * 8 + ccc + sh) & 31];
      g4[cg] = s;
    }
    const float iv = sigf(g4[0] + bias[j]);
    const float fv = sigf(g4[1] + bias[1024 + j]);
    const float gv = tanhf_(g4[2] + bias[2048 + j]);
    const float ov = sigf(g4[3] + bias[3072 + j]);
    const size_t idx = (size_t)row * 1024 + j;
    const float cc = fv * cbuf[idx] + iv * gv;
    cbuf[idx] = cc;
    const float hh = ov * tanhf_(cc);
    out_t[idx] = hh;
    // write next h in packed a-frag order
    const int kqm = j >> 8, ksj = (j >> 5) & 7, qj = (j >> 3) & 3, ej = j & 7;
    const int rhj = row >> 6, rfj = (row >> 4) & 3, rj = row & 15;
    hp_out[(size_t)((((rhj * 4 + kqm) * 8 + ksj) * 4 + rfj) * 64 + (qj * 16 + rj)) * 8 + ej] = f2bf(hh);
  }
}

extern "C" void kernel_launch(void* const* d_in, const int* in_sizes, int n_in,
                              void* d_out, int out_size, void* d_ws, size_t ws_size,
                              hipStream_t stream) {
  (void)in_sizes; (void)n_in; (void)out_size; (void)ws_size;
  const float* x    = (const float*)d_in[0];
  const float* w_ih = (const float*)d_in[1];
  const float* w_hh = (const float*)d_in[2];
  const float* b_ih = (const float*)d_in[3];
  const float* b_hh = (const float*)d_in[4];
  float* out = (float*)d_out;

  char* ws = (char*)d_ws;
  const size_t XP_OFF   = 0;                        // 512*131072*2  = 134217728
  const size_t WP_OFF   = XP_OFF + 134217728;       // 1048576*16    =  16777216
  const size_t BIAS_OFF = WP_OFF + 16777216;        // 16384
  const size_t C_OFF    = BIAS_OFF + 16384;         // 524288
  const size_t H0_OFF   = C_OFF + 524288;           // 262144
  const size_t H1_OFF   = H0_OFF + 262144;          // 262144   (total ~152 MB)

  unsigned short* xp   = (unsigned short*)(ws + XP_OFF);
  unsigned short* wp   = (unsigned short*)(ws + WP_OFF);
  float*          bias = (float*)(ws + BIAS_OFF);
  float*          cbuf = (float*)(ws + C_OFF);
  unsigned short* h0   = (unsigned short*)(ws + H0_OFF);
  unsigned short* h1   = (unsigned short*)(ws + H1_OFF);

  xpack_kernel<<<32768, 256, 0, stream>>>(x, xp);
  wpack_kernel<<<4096, 256, 0, stream>>>(w_hh, w_ih, wp);
  bias_sum_kernel<<<16, 256, 0, stream>>>(b_ih, b_hh, bias, 4096);
  hipMemsetAsync(cbuf, 0, 524288, stream);
  hipMemsetAsync(h0, 0, 262144, stream);

  unsigned short* hin = h0;
  unsigned short* hout = h1;
  for (int t = 0; t < S_LEN; ++t) {
    lstm_step<<<128, 512, 0, stream>>>(hin, xp + (size_t)t * 131072, wp, bias, cbuf,
                                       out + (size_t)t * 131072, hout);
    unsigned short* tmp = hin; hin = hout; hout = tmp;
  }

  // outputs: [S,B,H] | hN | cN
  hipMemcpyAsync(out + (size_t)S_LEN * 131072, out + (size_t)(S_LEN - 1) * 131072,
                 131072 * sizeof(float), hipMemcpyDeviceToDevice, stream);
  hipMemcpyAsync(out + (size_t)S_LEN * 131072 + 131072, cbuf,
                 131072 * sizeof(float), hipMemcpyDeviceToDevice, stream);
}